// Round 4
// baseline (585.012 us; speedup 1.0000x reference)
//
#include <hip/hip_runtime.h>
#include <hip/hip_bf16.h>
#include <stdint.h>

#define NTOK 2048
#define NE 64
#define TOPK 4
#define DM 512
#define DF 2048
#define TOTSLOT (NTOK*TOPK)   // 8192

typedef __bf16 bf16;
typedef __bf16 bf16x8 __attribute__((ext_vector_type(8)));
typedef __bf16 bf16x4 __attribute__((ext_vector_type(4)));
typedef float  f32x4  __attribute__((ext_vector_type(4)));

// ---------------- routing (4 cheap parallel kernels) ----------------

__global__ void k_zero(int* counts) { counts[threadIdx.x] = 0; }

__global__ void k_route(const float* __restrict__ hw, float* __restrict__ top_w,
                        int* __restrict__ top_idx, int* __restrict__ counts) {
  int t = blockIdx.x * blockDim.x + threadIdx.x;
  if (t >= NTOK) return;
  const float* r = hw + (size_t)t * NE;
  float rv[NE];
  #pragma unroll
  for (int e = 0; e < NE; ++e) rv[e] = r[e];
  float v[TOPK]; int id[TOPK];
  #pragma unroll
  for (int k = 0; k < TOPK; ++k) {
    float best = -1e30f; int bi = 0;
    #pragma unroll
    for (int e = 0; e < NE; ++e) {
      bool used = false;
      #pragma unroll
      for (int j = 0; j < k; ++j) used |= (id[j] == e);
      if (!used && rv[e] > best) { best = rv[e]; bi = e; }
    }
    v[k] = best; id[k] = bi;
  }
  float den = v[0] + v[1] + v[2] + v[3] + 1e-8f;   // matches ref
  #pragma unroll
  for (int k = 0; k < TOPK; ++k) {
    top_w[t*TOPK + k] = v[k] / den;
    top_idx[t*TOPK + k] = id[k];
    atomicAdd(&counts[id[k]], 1);
  }
}

__global__ void k_scan(const int* __restrict__ counts, int* __restrict__ offsets) {
  if (threadIdx.x == 0) {
    int a = 0;
    for (int e = 0; e < NE; ++e) { offsets[e] = a; a += counts[e]; }
    offsets[NE] = a;
  }
}

// one wave per expert; ballot-ordered deterministic CSR fill
__global__ void k_fill(const int* __restrict__ top_idx, const int* __restrict__ offsets,
                       int* __restrict__ tok, int* __restrict__ slot_of) {
  const int e = blockIdx.x;
  const int lane = threadIdx.x;       // 64
  int pos = offsets[e];
  for (int c = 0; c < TOTSLOT / 64; ++c) {
    int idx = c * 64 + lane;
    bool mine = (top_idx[idx] == e);
    unsigned long long m = __ballot(mine);
    if (mine) {
      int my = __popcll(m & ((1ull << lane) - 1ull));
      tok[pos + my] = idx >> 2;       // token = idx / TOPK
      slot_of[idx] = pos + my;
    }
    pos += __popcll(m);
  }
}

__global__ void k_xcast(const float* __restrict__ x, bf16* __restrict__ xb) {
  int i = blockIdx.x * blockDim.x + threadIdx.x;
  int base = i * 4;
  if (base >= NTOK * DM) return;
  float4 f = *(const float4*)(x + base);
  bf16x4 o;
  o[0] = (bf16)f.x; o[1] = (bf16)f.y; o[2] = (bf16)f.z; o[3] = (bf16)f.w;
  *(bf16x4*)(xb + base) = o;
}

// ---------------- barrier-free streaming grouped GEMM ----------------
// A (the reused operand: token rows, bf16) is staged in LDS ONCE
// (128 rows x 512 k = 128 KB, XOR-swizzled 16B units), one barrier total.
// B (fp32 weights) streams global->reg->cvt->MFMA; NO LDS, NO barriers in
// the K-loop -> waves free-run like a fillBuffer streamer.
// k64-permutation: lane (n=lcol, g=lane>>4) reads W[n][kb*64+g*16 .. +15]
// (64B contiguous); halves h=0/1 feed two MFMAs; A frags use the same k map.
// Block: 1024 thr = 16 waves (4m x 4n), wave tile 32x64, BM=128, BN=256.
// PASS1: KSPLIT=1 (K=512).  PASS2: KSPLIT=4 (KLOC=512), partial O buffers.
// Grid x = e*(NB*KSPLIT)+ntile*KSPLIT+ks, y = mblk: m-blocks share x%8 -> same
// XCD -> the B panel re-read by the second m-block hits that XCD's L2.

template<int PASS, int KSPLIT>
__global__ __launch_bounds__(1024, 4) void k_gemm(
    const float* __restrict__ W, const float* __restrict__ bias,
    const bf16* __restrict__ Asrc, const int* __restrict__ tok,
    const int* __restrict__ offsets,
    bf16* __restrict__ Hout, float* __restrict__ Oout)
{
  constexpr int KFULL = (PASS == 1) ? DM : DF;
  constexpr int NDIM  = (PASS == 1) ? DF : DM;
  constexpr int KLOC  = KFULL / KSPLIT;   // 512 both
  constexpr int NB    = NDIM / 256;       // 8 / 2
  constexpr int KB    = KLOC / 64;        // 8
  static_assert(KLOC == 512, "A-LDS sized for KLOC=512");

  const int bx    = blockIdx.x;
  const int e     = bx / (NB * KSPLIT);
  const int rem   = bx % (NB * KSPLIT);
  const int ntile = rem / KSPLIT;
  const int ks    = rem % KSPLIT;
  const int mblk  = blockIdx.y;

  const int off = offsets[e];
  const int cnt = offsets[e+1] - off;
  if (mblk * 128 >= cnt) return;
  const int rowcount = min(cnt - mblk * 128, 128);
  const int tid = threadIdx.x;

  __shared__ bf16 As[128 * 512];   // 128 KB

  // ---- stage A once: 128 rows x 64 16B-units; 8 units/thread ----
  #pragma unroll
  for (int q = 0; q < 8; ++q) {
    int id = q * 1024 + tid;
    int r = id >> 6, u = id & 63;
    int rr = min(r, rowcount - 1);
    int srcrow = (PASS == 1) ? tok[off + mblk*128 + rr] : (off + mblk*128 + rr);
    bf16x8 v = *(const bf16x8*)(Asrc + (size_t)srcrow * KFULL + ks * KLOC + u * 8);
    *(bf16x8*)(&As[r * 512 + ((u ^ (r & 7)) * 8)]) = v;
  }
  __syncthreads();   // the only barrier

  const int wave = tid >> 6, lane = tid & 63;
  const int wm = wave >> 2, wn = wave & 3;
  const int lcol = lane & 15, g = lane >> 4;

  const float* bp[4];
  #pragma unroll
  for (int j = 0; j < 4; ++j) {
    int n = ntile*256 + wn*64 + j*16 + lcol;
    bp[j] = W + (size_t)e * NDIM * KFULL + (size_t)n * KFULL + ks * KLOC + g * 16;
  }

  f32x4 acc[2][4] = {};

  #pragma unroll 2
  for (int kb = 0; kb < KB; ++kb) {
    bf16x8 af[2][2];
    #pragma unroll
    for (int i = 0; i < 2; ++i) {
      int m = wm*32 + i*16 + lcol;
      int ub = kb*8 + g*2;
      af[i][0] = *(const bf16x8*)(&As[m*512 + (( ub    ^ (m & 7)) * 8)]);
      af[i][1] = *(const bf16x8*)(&As[m*512 + (((ub+1) ^ (m & 7)) * 8)]);
    }
    #pragma unroll
    for (int j = 0; j < 4; ++j) {
      float4 b0 = *(const float4*)(bp[j] + kb*64);
      float4 b1 = *(const float4*)(bp[j] + kb*64 + 4);
      float4 b2 = *(const float4*)(bp[j] + kb*64 + 8);
      float4 b3 = *(const float4*)(bp[j] + kb*64 + 12);
      bf16x8 f0, f1;
      f0[0]=(bf16)b0.x; f0[1]=(bf16)b0.y; f0[2]=(bf16)b0.z; f0[3]=(bf16)b0.w;
      f0[4]=(bf16)b1.x; f0[5]=(bf16)b1.y; f0[6]=(bf16)b1.z; f0[7]=(bf16)b1.w;
      f1[0]=(bf16)b2.x; f1[1]=(bf16)b2.y; f1[2]=(bf16)b2.z; f1[3]=(bf16)b2.w;
      f1[4]=(bf16)b3.x; f1[5]=(bf16)b3.y; f1[6]=(bf16)b3.z; f1[7]=(bf16)b3.w;
      #pragma unroll
      for (int i = 0; i < 2; ++i) {
        acc[i][j] = __builtin_amdgcn_mfma_f32_16x16x32_bf16(af[i][0], f0, acc[i][j], 0, 0, 0);
        acc[i][j] = __builtin_amdgcn_mfma_f32_16x16x32_bf16(af[i][1], f1, acc[i][j], 0, 0, 0);
      }
    }
  }

  // ---- epilogue. C/D: col = lane&15, row = (lane>>4)*4 + reg ----
  const int slotbase = off + mblk * 128;
  #pragma unroll
  for (int i = 0; i < 2; ++i) {
    const int rbase = wm*32 + i*16 + g*4;
    #pragma unroll
    for (int j = 0; j < 4; ++j) {
      const int gcol = ntile*256 + wn*64 + j*16 + lcol;
      const float bv = (PASS == 2 && ks != 0) ? 0.0f : bias[(size_t)e * NDIM + gcol];
      #pragma unroll
      for (int q = 0; q < 4; ++q) {
        const int r = rbase + q;
        if (r < rowcount) {
          float h = acc[i][j][q] + bv;
          if (PASS == 1) {
            float s = h / (1.0f + __expf(-h));      // silu
            Hout[(size_t)(slotbase + r) * DF + gcol] = (bf16)s;
          } else {
            Oout[(size_t)ks * TOTSLOT * DM + (size_t)(slotbase + r) * DM + gcol] = h;
          }
        }
      }
    }
  }
}

// ---------------- combine (deterministic, sums 4 K-split partials) ----------------

__global__ void k_combine(const float* __restrict__ O, const float* __restrict__ top_w,
                          const int* __restrict__ slot_of, float* __restrict__ out) {
  int i = blockIdx.x * blockDim.x + threadIdx.x;
  if (i >= NTOK * DM / 4) return;
  int t  = i / (DM / 4);
  int d4 = (i % (DM / 4)) * 4;
  float4 s = {0.f, 0.f, 0.f, 0.f};
  #pragma unroll
  for (int k = 0; k < TOPK; ++k) {
    float w = top_w[t*TOPK + k];
    int  sl = slot_of[t*TOPK + k];
    float sx = 0.f, sy = 0.f, sz = 0.f, sw = 0.f;
    #pragma unroll
    for (int p = 0; p < 4; ++p) {
      float4 o = *(const float4*)(O + (size_t)p * TOTSLOT * DM + (size_t)sl * DM + d4);
      sx += o.x; sy += o.y; sz += o.z; sw += o.w;
    }
    s.x += w * sx; s.y += w * sy; s.z += w * sz; s.w += w * sw;
  }
  *(float4*)(out + (size_t)t * DM + d4) = s;
}

// ---------------- launch ----------------

extern "C" void kernel_launch(void* const* d_in, const int* in_sizes, int n_in,
                              void* d_out, int out_size, void* d_ws, size_t ws_size,
                              hipStream_t stream) {
  const float* x        = (const float*)d_in[0];
  const float* hw       = (const float*)d_in[1];
  const float* W_in     = (const float*)d_in[2];
  const float* bias_in  = (const float*)d_in[3];
  const float* W_out    = (const float*)d_in[4];
  const float* bias_out = (const float*)d_in[5];
  float* out = (float*)d_out;

  char* ws = (char*)d_ws;
  int*   counts  = (int*)  (ws + 0);                     // 64 ints
  int*   offsets = (int*)  (ws + 512);                   // 65 ints
  int*   top_idx = (int*)  (ws + 1024);                  // 32 KB
  float* top_w   = (float*)(ws + 1024 + 32768);          // 32 KB
  int*   slot_of = (int*)  (ws + 1024 + 2*32768);        // 32 KB
  int*   tok     = (int*)  (ws + 1024 + 3*32768);        // 32 KB
  bf16*  xb      = (bf16*) (ws + 1024 + 4*32768);        // 2 MB
  size_t o_xb_end = 1024 + 4*32768 + (size_t)NTOK*DM*2;
  bf16*  H       = (bf16*) (ws + o_xb_end);              // 32 MB
  size_t o_H_end  = o_xb_end + (size_t)TOTSLOT*DF*2;
  float* O       = (float*)(ws + o_H_end);               // 4 x 16 MB partials

  k_zero <<<1, NE, 0, stream>>>(counts);
  k_route<<<NTOK/256, 256, 0, stream>>>(hw, top_w, top_idx, counts);
  k_scan <<<1, 64, 0, stream>>>(counts, offsets);
  k_fill <<<NE, 64, 0, stream>>>(top_idx, offsets, tok, slot_of);
  k_xcast<<<(NTOK*DM/4)/256, 256, 0, stream>>>(x, xb);

  dim3 g1(NE * 8, 2);   // (e,ntile) x mblk ; KSPLIT=1, NB=8
  k_gemm<1,1><<<g1, 1024, 0, stream>>>(W_in, bias_in, xb, tok, offsets, H, nullptr);
  dim3 g2(NE * 8, 2);   // (e,ntile,ks) x mblk ; KSPLIT=4, NB=2
  k_gemm<2,4><<<g2, 1024, 0, stream>>>(W_out, bias_out, H, nullptr, offsets, nullptr, O);

  k_combine<<<(NTOK*DM/4)/256, 256, 0, stream>>>(O, top_w, slot_of, out);
}